// Round 3
// baseline (64.990 us; speedup 1.0000x reference)
//
#include <hip/hip_runtime.h>
#include <cfloat>

// DistLoss: out = sum_m min_{s,n} ||surfaces[s,n,:] - targets[m,:]||^2
// surfaces: [4,4096,3] f32 (flat SN=16384 points), targets: [16384,3] f32.
//
// R3: surface-point broadcast via SGPR (s_load) instead of LDS.
// The point stream is wave-uniform, so `const __restrict__` float4 loads at
// uniform indices compile to s_load_dwordx4 -> each v_fma reads the point
// component as its one allowed SGPR operand. No LDS, no __syncthreads.
//   d(m,p) = s2[p] + x[p]*(-2 tx[m]) + y[p]*(-2 ty[m]) + z[p]*(-2 tz[m])
// -> 3 fma/pair + min3 per 2 pairs = 1.5 VALU inst/pair (VALU floor ~5 us).
//
//  k0: pack surf -> spt[SN] = float4(x,y,z,s2)          (256 KB in ws)
//  k1: grid (8,128), 256 thr, T=8 targets/thread, CHUNK=128 points.
//  k2: 64 blocks: min over 128 chunks per target, block-sum -> part[64].
//  k3: 1 wave: sum part[64] -> out[0].
// No atomics -> deterministic.

namespace {
constexpr int M   = 16384;   // targets
constexpr int SN  = 16384;   // 4 * 4096 surface points
constexpr int TPB = 256;
constexpr int T   = 8;                     // targets per thread
constexpr int TGT_PER_BLOCK = TPB * T;     // 2048
constexpr int NCHUNK = 128;
constexpr int CHUNK  = SN / NCHUNK;        // 128
}

__global__ __launch_bounds__(256) void pack_points(
    const float* __restrict__ surf,   // [SN][3]
    float4* __restrict__ spt)         // [SN] (x,y,z,s2)
{
  const int i = blockIdx.x * 256 + threadIdx.x;
  const float x = surf[(size_t)i * 3 + 0];
  const float y = surf[(size_t)i * 3 + 1];
  const float z = surf[(size_t)i * 3 + 2];
  spt[i] = make_float4(x, y, z, fmaf(x, x, fmaf(y, y, z * z)));
}

__global__ __launch_bounds__(TPB) void dist_partial_min(
    const float4* __restrict__ spt,   // [SN] packed points (uniform reads)
    const float* __restrict__ tgt,    // [M][3]
    float* __restrict__ wmin)         // [NCHUNK][M]
{
  const int tid   = threadIdx.x;
  const int mbase = blockIdx.x * TGT_PER_BLOCK;
  const int cbase = blockIdx.y * CHUNK;

  float tx[T], ty[T], tz[T], b2[T], mn[T];
#pragma unroll
  for (int j = 0; j < T; ++j) {
    const int m     = mbase + j * TPB + tid;
    const float* tp = tgt + (size_t)m * 3;
    const float a = tp[0], b = tp[1], c = tp[2];
    tx[j] = -2.0f * a; ty[j] = -2.0f * b; tz[j] = -2.0f * c;
    b2[j] = fmaf(a, a, fmaf(b, b, c * c));
    mn[j] = FLT_MAX;
  }

  for (int p = 0; p < CHUNK; p += 4) {
    // wave-uniform indices -> scalar loads (s_load_dwordx4)
    const float4 P0 = spt[cbase + p + 0];
    const float4 P1 = spt[cbase + p + 1];
    const float4 P2 = spt[cbase + p + 2];
    const float4 P3 = spt[cbase + p + 3];
#pragma unroll
    for (int j = 0; j < T; ++j) {
      const float d0 = fmaf(P0.x, tx[j], fmaf(P0.y, ty[j], fmaf(P0.z, tz[j], P0.w)));
      const float d1 = fmaf(P1.x, tx[j], fmaf(P1.y, ty[j], fmaf(P1.z, tz[j], P1.w)));
      const float d2 = fmaf(P2.x, tx[j], fmaf(P2.y, ty[j], fmaf(P2.z, tz[j], P2.w)));
      const float d3 = fmaf(P3.x, tx[j], fmaf(P3.y, ty[j], fmaf(P3.z, tz[j], P3.w)));
      mn[j] = fminf(fminf(mn[j], d0), d1);   // v_min3_f32
      mn[j] = fminf(fminf(mn[j], d2), d3);   // v_min3_f32
    }
  }

#pragma unroll
  for (int j = 0; j < T; ++j)
    wmin[(size_t)blockIdx.y * M + mbase + j * TPB + tid] = mn[j] + b2[j];
}

__global__ __launch_bounds__(256) void dist_min_sum(
    const float* __restrict__ wmin,   // [NCHUNK][M]
    float* __restrict__ part)         // [64]
{
  const int tid = threadIdx.x;
  const int m   = blockIdx.x * 256 + tid;

  float mnv = FLT_MAX;
  for (int c = 0; c < NCHUNK; ++c)
    mnv = fminf(mnv, wmin[(size_t)c * M + m]);

  float sum = mnv;
  for (int off = 32; off; off >>= 1) sum += __shfl_down(sum, off, 64);

  __shared__ float red[4];
  if ((tid & 63) == 0) red[tid >> 6] = sum;
  __syncthreads();
  if (tid == 0) part[blockIdx.x] = red[0] + red[1] + red[2] + red[3];
}

__global__ __launch_bounds__(64) void dist_final(
    const float* __restrict__ part, float* __restrict__ out)
{
  float v = part[threadIdx.x];
  for (int off = 32; off; off >>= 1) v += __shfl_down(v, off, 64);
  if (threadIdx.x == 0) out[0] = v;
}

extern "C" void kernel_launch(void* const* d_in, const int* in_sizes, int n_in,
                              void* d_out, int out_size, void* d_ws, size_t ws_size,
                              hipStream_t stream) {
  const float* surf = (const float*)d_in[0];   // 4*4096*3
  const float* tgt  = (const float*)d_in[1];   // 16384*3
  float* out  = (float*)d_out;

  float4* spt = (float4*)d_ws;                              // 256 KB
  float*  wmin = (float*)(spt + SN);                        // NCHUNK*M floats = 8 MB
  float*  part = wmin + (size_t)NCHUNK * M;                 // 64 floats

  pack_points<<<SN / 256, 256, 0, stream>>>(surf, spt);
  dim3 g1(M / TGT_PER_BLOCK, NCHUNK);
  dist_partial_min<<<g1, TPB, 0, stream>>>(spt, tgt, wmin);
  dist_min_sum<<<M / 256, 256, 0, stream>>>(wmin, part);
  dist_final<<<1, 64, 0, stream>>>(part, out);
}